// Round 3
// baseline (430.800 us; speedup 1.0000x reference)
//
#include <hip/hip_runtime.h>
#include <hip/hip_bf16.h>

// GNN_LinearAttn: B=8, N=2048, D=512, fp32 in/out, bf16 MFMA internally.
//
// Pipeline (5 graph nodes):
//  K1 gate:   deg=rowsum(adj); xg = x * sigmoid(deg*Wd + bd)       (bf16)
//             + folded Wqk/Wl/Wr fp32->bf16 casts
//  K2 transp: xgT[b,d,n] = xg[b,n,d]                               (bf16)
//  K3 gemm8:  QK = sigmoid(xg @ Wqk^T + bqk)                       (bf16)
//  K4 attn:   FLASH-FUSED  h = (Pmask @ xg) / (rowsum(Pmask)+1e-6)
//             where Pmask = bf16((QK QK^T)/sqrt(D) * adj) -- S NEVER
//             materialized (was 67MB write + ~270MB read + atomics).
//  K5 gemm8:  out = relu(h @ Wl^T + bl + xg @ Wr^T)   [one NT=16 pipeline]
//
// k_attn: 256 blocks (1/CU) = 8 batches x 32 row-tiles (64 Q-rows). b=id&7
// -> one batch per XCD; QK[b]+xgT[b] = 4MB = that XCD's L2. Per j-tile
// (256 cols): T-step reads QK_i from swizzled LDS + QK_j direct from L2
// (full-64B-line lane groups); P = bf16(T*scale*adj) with adj prefetched
// to regs at tile start (latency hidden under T's MFMAs); P -> padded LDS;
// PV reads P as A-frags + xgT direct from L2. denom in-register (no
// atomics), divided out in the epilogue. LDS 99.3KB, 8 waves, ~200 VGPR.

typedef __bf16 bf16;
typedef __bf16 bf16x2 __attribute__((ext_vector_type(2)));
typedef __bf16 bf16x8 __attribute__((ext_vector_type(8)));
typedef float  f32x4  __attribute__((ext_vector_type(4)));

#define Bb 8
#define Nn 2048
#define Dd 512
#define TILE8_BYTES 49152    // gemm8: A 256x64x2 (32KB) + B 128x64x2 (16KB)
#define SMEM8_BYTES (3 * TILE8_BYTES)   // 147456
#define ATTN_SMEM (65536 + 33792 + 2048 + 256)   // 101632

__device__ __forceinline__ bf16 to_bf16(float f) { return (bf16)f; }
__device__ __forceinline__ float sigmoidf_(float x) { return 1.0f / (1.0f + __expf(-x)); }

__device__ __forceinline__ void gld16(const void* g, void* l) {
    __builtin_amdgcn_global_load_lds(
        (__attribute__((address_space(1))) void*)(void*)g,
        (__attribute__((address_space(3))) void*)l,
        16, 0, 0);
}

// ---------------- gemm8 core: 256x128, 8 waves, triple-buffered ----------
__device__ __forceinline__ void gemm_bt8_core(
    const bf16* __restrict__ A0, const bf16* __restrict__ B0,
    int lda0, int ldb0, int nt0,
    const bf16* __restrict__ A1, const bf16* __restrict__ B1,
    int lda1, int ldb1, int nt1,
    char* smem, f32x4 acc[4][4])
{
    const int tid  = threadIdx.x;          // 0..511
    const int lane = tid & 63;
    const int wave = tid >> 6;             // 0..7
    const int wm = (wave >> 1) << 6;       // 0,64,128,192
    const int wn = (wave & 1) << 6;        // 0,64
    const int NT = nt0 + nt1;

    char* bA = smem;
    char* bB = smem + TILE8_BYTES;
    char* bC = smem + 2 * TILE8_BYTES;

    auto stage_tile = [&](char* base, int t) {
        const bf16* A  = (t < nt0) ? A0 : A1;
        const bf16* Bt = (t < nt0) ? B0 : B1;
        const int lda  = (t < nt0) ? lda0 : lda1;
        const int ldb  = (t < nt0) ? ldb0 : ldb1;
        const int kt   = ((t < nt0) ? t : t - nt0) << 6;
#pragma unroll
        for (int i = 0; i < 4; ++i) {
            int ff   = i * 512 + tid;                // A: 2048 16B-chunks
            int row  = ff >> 3;
            int slot = ff & 7;
            int gch  = slot ^ (row & 7);
            gld16(A + (size_t)row * lda + kt + gch * 8, base + ff * 16);
        }
#pragma unroll
        for (int i = 0; i < 2; ++i) {
            int ff   = i * 512 + tid;                // B: 1024 16B-chunks
            int row  = ff >> 3;
            int slot = ff & 7;
            int gch  = slot ^ (row & 7);
            gld16(Bt + (size_t)row * ldb + kt + gch * 8, base + 32768 + ff * 16);
        }
    };

    stage_tile(bA, 0);
    stage_tile(bB, 1);
    asm volatile("s_waitcnt vmcnt(6)" ::: "memory");
    __builtin_amdgcn_s_barrier();

#pragma unroll 1
    for (int t = 0; t < NT; ++t) {
        bf16x8 af0[4], bf0[4], af1[4], bf1[4];
#pragma unroll
        for (int mi = 0; mi < 4; ++mi) {
            int row  = wm + mi * 16 + (lane & 15);
            int slot = (lane >> 4) ^ (row & 7);
            af0[mi] = *(const bf16x8*)(bA + row * 128 + slot * 16);
        }
#pragma unroll
        for (int ni = 0; ni < 4; ++ni) {
            int row  = wn + ni * 16 + (lane & 15);
            int slot = (lane >> 4) ^ (row & 7);
            bf0[ni] = *(const bf16x8*)(bA + 32768 + row * 128 + slot * 16);
        }
        if (t + 2 < NT) stage_tile(bC, t + 2);
        __builtin_amdgcn_s_barrier();
        asm volatile("s_waitcnt lgkmcnt(0)" ::: "memory");
        __builtin_amdgcn_sched_barrier(0);
#pragma unroll
        for (int mi = 0; mi < 4; ++mi) {
            int row  = wm + mi * 16 + (lane & 15);
            int slot = (4 + (lane >> 4)) ^ (row & 7);
            af1[mi] = *(const bf16x8*)(bA + row * 128 + slot * 16);
        }
#pragma unroll
        for (int ni = 0; ni < 4; ++ni) {
            int row  = wn + ni * 16 + (lane & 15);
            int slot = (4 + (lane >> 4)) ^ (row & 7);
            bf1[ni] = *(const bf16x8*)(bA + 32768 + row * 128 + slot * 16);
        }
        __builtin_amdgcn_sched_barrier(0);
        __builtin_amdgcn_s_setprio(1);
#pragma unroll
        for (int mi = 0; mi < 4; ++mi)
#pragma unroll
            for (int ni = 0; ni < 4; ++ni)
                acc[mi][ni] = __builtin_amdgcn_mfma_f32_16x16x32_bf16(
                    af0[mi], bf0[ni], acc[mi][ni], 0, 0, 0);
        __builtin_amdgcn_s_setprio(0);
        asm volatile("s_waitcnt lgkmcnt(0)" ::: "memory");
        __builtin_amdgcn_sched_barrier(0);
        __builtin_amdgcn_s_setprio(1);
#pragma unroll
        for (int mi = 0; mi < 4; ++mi)
#pragma unroll
            for (int ni = 0; ni < 4; ++ni)
                acc[mi][ni] = __builtin_amdgcn_mfma_f32_16x16x32_bf16(
                    af1[mi], bf1[ni], acc[mi][ni], 0, 0, 0);
        __builtin_amdgcn_s_setprio(0);
        __builtin_amdgcn_sched_barrier(0);
        if (t + 2 < NT)      asm volatile("s_waitcnt vmcnt(6)" ::: "memory");
        else if (t + 1 < NT) asm volatile("s_waitcnt vmcnt(0)" ::: "memory");
        __builtin_amdgcn_s_barrier();
        char* tmp = bA; bA = bB; bB = bC; bC = tmp;
    }
}

// 256-row LDS-roundtrip epilogue: 4 phases of 64 rows, fp32 [64][132].
template <typename F>
__device__ __forceinline__ void epilogue_rt8(f32x4 acc[4][4], char* smem, F&& emit)
{
    const int tid  = threadIdx.x;
    const int lane = tid & 63;
    const int wave = tid >> 6;
    const int wm4 = wave >> 1;
    const int wn  = (wave & 1) << 6;
    const int cq = lane >> 4;
    const int cl = lane & 15;
    float* t = (float*)smem;
    const int chunk = tid & 15;
    const int rbase = tid >> 4;
#pragma unroll
    for (int ph = 0; ph < 4; ++ph) {
        __syncthreads();
        if (wm4 == ph) {
#pragma unroll
            for (int mi = 0; mi < 4; ++mi)
#pragma unroll
                for (int ni = 0; ni < 4; ++ni)
#pragma unroll
                    for (int r = 0; r < 4; ++r) {
                        int lr = mi * 16 + cq * 4 + r;
                        int lc = wn + ni * 16 + cl;
                        t[lr * 132 + lc] = acc[mi][ni][r];
                    }
        }
        __syncthreads();
#pragma unroll
        for (int rr = 0; rr < 2; ++rr) {
            int lr = rr * 32 + rbase;
            f32x4 a = *(const f32x4*)&t[lr * 132 + chunk * 8];
            f32x4 b = *(const f32x4*)&t[lr * 132 + chunk * 8 + 4];
            float v[8] = {a[0], a[1], a[2], a[3], b[0], b[1], b[2], b[3]};
            emit(ph * 64 + lr, chunk * 8, v);
        }
    }
}

// ---------- K1: deg + gate + xg  (+ folded weight casts) ----------
__global__ __launch_bounds__(256) void k_gate(
    const float* __restrict__ x, const float* __restrict__ adj,
    const float* __restrict__ Wd, const float* __restrict__ bd,
    const float* __restrict__ Wqk, const float* __restrict__ Wl,
    const float* __restrict__ Wr,
    bf16* __restrict__ xg, bf16* __restrict__ Wqkb, bf16* __restrict__ Wlb,
    bf16* __restrict__ Wrb)
{
    const int rowg = blockIdx.x;                   // b*N + n  (16384 blocks)
    const int tid  = threadIdx.x;
    if (tid < 48) {
        int idx = rowg * 48 + tid;
        if (idx < 262144)      Wqkb[idx]          = to_bf16(Wqk[idx]);
        else if (idx < 524288) Wlb[idx - 262144]  = to_bf16(Wl[idx - 262144]);
        else                   Wrb[idx - 524288]  = to_bf16(Wr[idx - 524288]);
    }

    const float4* arow = (const float4*)(adj + (size_t)rowg * Nn);
    float4 v0 = arow[tid];
    float4 v1 = arow[tid + 256];
    float s = v0.x + v0.y + v0.z + v0.w + v1.x + v1.y + v1.z + v1.w;
#pragma unroll
    for (int off = 32; off > 0; off >>= 1) s += __shfl_down(s, off, 64);
    __shared__ float red[4];
    if ((tid & 63) == 0) red[tid >> 6] = s;
    __syncthreads();
    const float deg = red[0] + red[1] + red[2] + red[3];
    const int d2 = tid;
    float2 xv  = ((const float2*)(x + (size_t)rowg * Dd))[d2];
    float2 wd  = ((const float2*)Wd)[d2];
    float2 bd2 = ((const float2*)bd)[d2];
    bf16x2 o;
    o[0] = to_bf16(xv.x * sigmoidf_(deg * wd.x + bd2.x));
    o[1] = to_bf16(xv.y * sigmoidf_(deg * wd.y + bd2.y));
    *(bf16x2*)(xg + (size_t)rowg * Dd + d2 * 2) = o;
}

// ---------------- K2: transpose xg -> xgT ----------------
__global__ __launch_bounds__(256) void k_transpose(
    const bf16* __restrict__ xg, bf16* __restrict__ xgT)
{
    const int b = blockIdx.z, nt = blockIdx.y, dt = blockIdx.x;
    __shared__ bf16 tile[64][66];
    const int c = threadIdx.x & 63, r0 = threadIdx.x >> 6;
    const bf16* src = xg + ((size_t)b * Nn + nt * 64) * Dd + dt * 64;
#pragma unroll
    for (int i = 0; i < 16; ++i) {
        int r = i * 4 + r0;
        tile[r][c] = src[(size_t)r * Dd + c];
    }
    __syncthreads();
    bf16* dst = xgT + ((size_t)b * Dd + dt * 64) * Nn + nt * 64;
#pragma unroll
    for (int i = 0; i < 16; ++i) {
        int r = i * 4 + r0;
        dst[(size_t)r * Nn + c] = tile[c][r];
    }
}

// ---------------- K3: QK = sigmoid(xg @ Wqk^T + bqk) [gemm8] ----------------
__global__ __launch_bounds__(512) void k_qk_gemm8(
    const bf16* __restrict__ xg, const bf16* __restrict__ Wqkb,
    const float* __restrict__ bqk, bf16* __restrict__ QK)
{
    extern __shared__ __align__(16) char smem[];
    const int blockRow = blockIdx.y * 256;
    const int blockCol = blockIdx.x * 128;
    f32x4 acc[4][4];
#pragma unroll
    for (int mi = 0; mi < 4; ++mi)
#pragma unroll
        for (int ni = 0; ni < 4; ++ni) acc[mi][ni] = (f32x4){0.f, 0.f, 0.f, 0.f};
    gemm_bt8_core(xg + (size_t)blockRow * Dd, Wqkb + (size_t)blockCol * Dd,
                  Dd, Dd, 8,
                  xg, Wqkb, Dd, Dd, 0, smem, acc);
    epilogue_rt8(acc, smem, [&](int lr, int lc, float* v) {
        int c = blockCol + lc;
        float4 b0 = *(const float4*)(bqk + c);
        float4 b1 = *(const float4*)(bqk + c + 4);
        float bb[8] = {b0.x, b0.y, b0.z, b0.w, b1.x, b1.y, b1.z, b1.w};
        bf16x8 o;
#pragma unroll
        for (int j = 0; j < 8; ++j) o[j] = to_bf16(sigmoidf_(v[j] + bb[j]));
        *(bf16x8*)(QK + (size_t)(blockRow + lr) * Dd + c) = o;
    });
}

// ------------- K4: fused masked-attention (S never materialized) -----------
// h[r,:] = (sum_j P[r,j] * xg[j,:]) / (sum_j P[r,j] + 1e-6),
// P[r,j] = bf16( (QK[r]. QK[j]) * scale * adj[r,j] )
__global__ __launch_bounds__(512) void k_attn(
    const bf16* __restrict__ QK, const bf16* __restrict__ xgT,
    const float* __restrict__ adj, bf16* __restrict__ h)
{
    extern __shared__ __align__(16) char smem[];
    char*  qki  = smem;                              // [64][512] bf16 swz, 65536
    char*  Pl   = smem + 65536;                      // [64][264] bf16, 33792
    float* dred = (float*)(smem + 65536 + 33792);    // [8][64]
    float* dinv = (float*)(smem + 65536 + 33792 + 2048);  // [64]

    const int id   = blockIdx.x;          // 0..255
    const int b    = id & 7;              // one batch per XCD (heuristic)
    const int row0 = (id >> 3) * 64;      // Q-row tile
    const int tid  = threadIdx.x;
    const int lane = tid & 63, w = tid >> 6;
    const int cq = lane >> 4, cl = lane & 15;

    const bf16*  QKb  = QK  + (size_t)b * Nn * Dd;
    const bf16*  QKi  = QKb + (size_t)row0 * Dd;
    const bf16*  xgTb = xgT + (size_t)b * Dd * Nn;
    const float* adjb = adj + (size_t)b * Nn * Nn + (size_t)row0 * Nn;

    // stage QK_i (64x512 bf16) into LDS, XOR-chunk swizzled within 8-groups
#pragma unroll
    for (int i = 0; i < 8; ++i) {
        int ff = i * 512 + tid;
        int row = ff >> 6, slot = ff & 63;
        int gch = (slot & 56) | ((slot & 7) ^ (row & 7));
        gld16(QKi + (size_t)row * Dd + gch * 8, qki + ff * 16);
    }

    f32x4 hacc[4][4];   // rows mi*16+cq*4+r, cols w*64+ni*16+cl
#pragma unroll
    for (int mi = 0; mi < 4; ++mi)
#pragma unroll
        for (int ni = 0; ni < 4; ++ni) hacc[mi][ni] = (f32x4){0.f, 0.f, 0.f, 0.f};
    float dloc[16];
#pragma unroll
    for (int i = 0; i < 16; ++i) dloc[i] = 0.f;
    float acur[2][16];

    __syncthreads();    // qki resident (compiler drains vmcnt before barrier)

    const float scale = 0.044194173824159216f;   // 1/sqrt(512)

#pragma unroll 1
    for (int jt = 0; jt < 8; ++jt) {
        const int j0 = jt * 256;
        // adj prefetch for THIS tile: issued now, consumed after T (~5k cyc)
#pragma unroll
        for (int nf = 0; nf < 2; ++nf)
#pragma unroll
            for (int mi = 0; mi < 4; ++mi)
#pragma unroll
                for (int r = 0; r < 4; ++r)
                    acur[nf][mi * 4 + r] =
                        adjb[(size_t)(mi * 16 + cq * 4 + r) * Nn + j0 + w * 32 + nf * 16 + cl];

        // T-step: T[64 x 256], wave w owns cols [w*32, w*32+32)
        f32x4 tacc[2][4];
#pragma unroll
        for (int nf = 0; nf < 2; ++nf)
#pragma unroll
            for (int mi = 0; mi < 4; ++mi) tacc[nf][mi] = (f32x4){0.f, 0.f, 0.f, 0.f};
#pragma unroll
        for (int kc = 0; kc < 16; ++kc) {
            bf16x8 af[4], bq[2];
#pragma unroll
            for (int nf = 0; nf < 2; ++nf)
                bq[nf] = *(const bf16x8*)(QKb
                    + (size_t)(j0 + w * 32 + nf * 16 + cl) * Dd + kc * 32 + cq * 8);
#pragma unroll
            for (int mi = 0; mi < 4; ++mi) {
                int row = mi * 16 + cl;
                int chunk = kc * 4 + cq;
                int slot = (chunk & 56) | ((chunk & 7) ^ (row & 7));
                af[mi] = *(const bf16x8*)(qki + row * 1024 + slot * 16);
            }
#pragma unroll
            for (int nf = 0; nf < 2; ++nf)
#pragma unroll
                for (int mi = 0; mi < 4; ++mi)
                    tacc[nf][mi] = __builtin_amdgcn_mfma_f32_16x16x32_bf16(
                        af[mi], bq[nf], tacc[nf][mi], 0, 0, 0);
        }
        __syncthreads();   // PV(jt-1) finished reading Pl
        // phase B: P = bf16(T*scale*adj) -> Pl; accumulate denom partials
#pragma unroll
        for (int nf = 0; nf < 2; ++nf)
#pragma unroll
            for (int mi = 0; mi < 4; ++mi)
#pragma unroll
                for (int r = 0; r < 4; ++r) {
                    float s = tacc[nf][mi][r] * scale * acur[nf][mi * 4 + r];
                    bf16 sb = to_bf16(s);
                    *(bf16*)(Pl + (mi * 16 + cq * 4 + r) * 528
                                + (w * 32 + nf * 16 + cl) * 2) = sb;
                    dloc[mi * 4 + r] += (float)sb;
                }
        __syncthreads();   // Pl ready for all waves
        // PV: hacc += P[64x256] @ xgT[d, j0..j0+256]^T
#pragma unroll
        for (int kc = 0; kc < 8; ++kc) {
            bf16x8 pa[4], xb[4];
#pragma unroll
            for (int mi = 0; mi < 4; ++mi)
                pa[mi] = *(const bf16x8*)(Pl + (mi * 16 + cl) * 528 + kc * 64 + cq * 16);
#pragma unroll
            for (int ni = 0; ni < 4; ++ni)
                xb[ni] = *(const bf16x8*)(xgTb
                    + (size_t)(w * 64 + ni * 16 + cl) * Nn + j0 + kc * 32 + cq * 8);
#pragma unroll
            for (int mi = 0; mi < 4; ++mi)
#pragma unroll
                for (int ni = 0; ni < 4; ++ni)
                    hacc[mi][ni] = __builtin_amdgcn_mfma_f32_16x16x32_bf16(
                        pa[mi], xb[ni], hacc[mi][ni], 0, 0, 0);
        }
    }

    // denom: reduce over 16 cols within cq-group, then across 8 waves
#pragma unroll
    for (int i = 0; i < 16; ++i)
#pragma unroll
        for (int off = 1; off < 16; off <<= 1)
            dloc[i] += __shfl_xor(dloc[i], off, 64);
    if (cl == 0) {
#pragma unroll
        for (int mi = 0; mi < 4; ++mi)
#pragma unroll
            for (int r = 0; r < 4; ++r)
                dred[w * 64 + mi * 16 + cq * 4 + r] = dloc[mi * 4 + r];
    }
    __syncthreads();
    if (tid < 64) {
        float s = 0.f;
#pragma unroll
        for (int k = 0; k < 8; ++k) s += dred[k * 64 + tid];
        dinv[tid] = 1.0f / (s + 1e-6f);
    }
    __syncthreads();

    // h write: two 32-row phases through LDS fp32 [32][516] (aliases qki/Pl)
    float* hs = (float*)smem;
#pragma unroll
    for (int p = 0; p < 2; ++p) {
        if (p) __syncthreads();
#pragma unroll
        for (int m2 = 0; m2 < 2; ++m2) {
            int mi = p * 2 + m2;
#pragma unroll
            for (int r = 0; r < 4; ++r) {
                float iv = dinv[mi * 16 + cq * 4 + r];
                int lrow = m2 * 16 + cq * 4 + r;
#pragma unroll
                for (int ni = 0; ni < 4; ++ni)
                    hs[lrow * 516 + w * 64 + ni * 16 + cl] = hacc[mi][ni][r] * iv;
            }
        }
        __syncthreads();
        {
            int row = tid & 31, ch = tid >> 5;
            int grow = row0 + p * 32 + row;
            bf16* dst = h + ((size_t)b * Nn + grow) * Dd + ch * 32;
            const float* src = hs + row * 516 + ch * 32;
#pragma unroll
            for (int g = 0; g < 4; ++g) {
                f32x4 u = *(const f32x4*)(src + g * 8);
                f32x4 q = *(const f32x4*)(src + g * 8 + 4);
                bf16x8 o;
                o[0] = to_bf16(u[0]); o[1] = to_bf16(u[1]);
                o[2] = to_bf16(u[2]); o[3] = to_bf16(u[3]);
                o[4] = to_bf16(q[0]); o[5] = to_bf16(q[1]);
                o[6] = to_bf16(q[2]); o[7] = to_bf16(q[3]);
                *(bf16x8*)(dst + g * 8) = o;
            }
        }
    }
}

// -------- K5: out = relu(h @ Wl^T + bl + xg @ Wr^T) [gemm8, NT=16] --------
__global__ __launch_bounds__(512) void k_out_gemm8(
    const bf16* __restrict__ h, const bf16* __restrict__ xg,
    const bf16* __restrict__ Wlb, const bf16* __restrict__ Wrb,
    const float* __restrict__ bl, float* __restrict__ out)
{
    extern __shared__ __align__(16) char smem[];
    const int blockRow = blockIdx.y * 256;
    const int blockCol = blockIdx.x * 128;
    f32x4 acc[4][4];
#pragma unroll
    for (int mi = 0; mi < 4; ++mi)
#pragma unroll
        for (int ni = 0; ni < 4; ++ni) acc[mi][ni] = (f32x4){0.f, 0.f, 0.f, 0.f};
    gemm_bt8_core(h  + (size_t)blockRow * Dd, Wlb + (size_t)blockCol * Dd,
                  Dd, Dd, 8,
                  xg + (size_t)blockRow * Dd, Wrb + (size_t)blockCol * Dd,
                  Dd, Dd, 8, smem, acc);
    epilogue_rt8(acc, smem, [&](int lr, int lc, float* v) {
        int c = blockCol + lc;
        float4 b0 = *(const float4*)(bl + c);
        float4 b1 = *(const float4*)(bl + c + 4);
        float bb[8] = {b0.x, b0.y, b0.z, b0.w, b1.x, b1.y, b1.z, b1.w};
        float4 o0, o1;
        o0.x = fmaxf(v[0] + bb[0], 0.f); o0.y = fmaxf(v[1] + bb[1], 0.f);
        o0.z = fmaxf(v[2] + bb[2], 0.f); o0.w = fmaxf(v[3] + bb[3], 0.f);
        o1.x = fmaxf(v[4] + bb[4], 0.f); o1.y = fmaxf(v[5] + bb[5], 0.f);
        o1.z = fmaxf(v[6] + bb[6], 0.f); o1.w = fmaxf(v[7] + bb[7], 0.f);
        float* p = out + (size_t)(blockRow + lr) * Dd + c;
        *(float4*)p = o0;
        *(float4*)(p + 4) = o1;
    });
}

extern "C" void kernel_launch(void* const* d_in, const int* in_sizes, int n_in,
                              void* d_out, int out_size, void* d_ws, size_t ws_size,
                              hipStream_t stream) {
    const float* x   = (const float*)d_in[0];
    const float* adj = (const float*)d_in[1];
    const float* Wqk = (const float*)d_in[2];
    const float* bqk = (const float*)d_in[3];
    const float* Wl  = (const float*)d_in[4];
    const float* bl  = (const float*)d_in[5];
    const float* Wr  = (const float*)d_in[6];
    const float* Wd  = (const float*)d_in[7];
    const float* bd  = (const float*)d_in[8];
    float* out = (float*)d_out;

    char* ws = (char*)d_ws;
    bf16* xg   = (bf16*)ws;  ws += (size_t)Bb * Nn * Dd * 2;   // 16.78 MB
    bf16* xgT  = (bf16*)ws;  ws += (size_t)Bb * Dd * Nn * 2;   // 16.78 MB
    bf16* QK   = (bf16*)ws;  ws += (size_t)Bb * Nn * Dd * 2;   // 16.78 MB
    bf16* h    = (bf16*)ws;  ws += (size_t)Bb * Nn * Dd * 2;   // 16.78 MB
    bf16* Wqkb = (bf16*)ws;  ws += (size_t)Dd * Dd * 2;
    bf16* Wlb  = (bf16*)ws;  ws += (size_t)Dd * Dd * 2;
    bf16* Wrb  = (bf16*)ws;  ws += (size_t)Dd * Dd * 2;

    static bool attr_done = false;
    if (!attr_done) {
        hipFuncSetAttribute((const void*)k_qk_gemm8,
                            hipFuncAttributeMaxDynamicSharedMemorySize, SMEM8_BYTES);
        hipFuncSetAttribute((const void*)k_attn,
                            hipFuncAttributeMaxDynamicSharedMemorySize, ATTN_SMEM);
        hipFuncSetAttribute((const void*)k_out_gemm8,
                            hipFuncAttributeMaxDynamicSharedMemorySize, SMEM8_BYTES);
        attr_done = true;
    }

    k_gate<<<dim3(Bb * Nn), 256, 0, stream>>>(x, adj, Wd, bd, Wqk, Wl, Wr,
                                              xg, Wqkb, Wlb, Wrb);
    k_transpose<<<dim3(Dd / 64, Nn / 64, Bb), 256, 0, stream>>>(xg, xgT);
    k_qk_gemm8<<<dim3(Dd / 128, (Bb * Nn) / 256), 512, SMEM8_BYTES, stream>>>(xg, Wqkb, bqk, QK);
    k_attn<<<dim3(256), 512, ATTN_SMEM, stream>>>(QK, xgT, adj, h);
    k_out_gemm8<<<dim3(Dd / 128, (Bb * Nn) / 256), 512, SMEM8_BYTES, stream>>>(h, xg, Wlb, Wrb, bl, out);
}